// Round 8
// baseline (511.073 us; speedup 1.0000x reference)
//
#include <hip/hip_runtime.h>
#include <hip/hip_bf16.h>
#include <stdint.h>

#define S 4096
#define E 512
#define H 8
#define D 64
#define MROW 5000        // mask row stride (MAX_GENES)

typedef __hip_bfloat16 bf16;
typedef __attribute__((ext_vector_type(8))) short bf16x8;
typedef __attribute__((ext_vector_type(4))) float f32x4;

#define CMUL (0.125f * 1.4426950408889634f)  // scale * log2(e), folded into Q

// ---------------------------------------------------------------------------
// prep: all 2048 blocks convert fp32->bf16 (12 MB) via branch-structured
// segment select, then pack mask into TRANSPOSED bit matrix bitsT[word][row].
// ---------------------------------------------------------------------------
__global__ __launch_bounds__(256) void prep(
    const void* __restrict__ mask, unsigned long long* __restrict__ bitsT,
    const float* __restrict__ x,  const float* __restrict__ wq,
    const float* __restrict__ wk, const float* __restrict__ wv,
    const float* __restrict__ wo, const float* __restrict__ bq,
    const float* __restrict__ bk, const float* __restrict__ bv,
    const float* __restrict__ bo,
    bf16* __restrict__ xb, bf16* __restrict__ wcat, bf16* __restrict__ wob,
    bf16* __restrict__ bcat, bf16* __restrict__ bob)
{
    const int tid = threadIdx.x;
    const int b   = blockIdx.x;
    const int gid = b * 256 + tid;
    for (int g = gid; g < 786944; g += 524288) {
        const float* src; bf16* dst; int e;
        if (g < 524288) { src = x; dst = xb; e = g * 4; }
        else {
            int r = g - 524288;
            if      (r < 65536)  { src = wq; dst = wcat;          e = r * 4; }
            else if (r < 131072) { src = wk; dst = wcat + 262144; e = (r - 65536) * 4; }
            else if (r < 196608) { src = wv; dst = wcat + 524288; e = (r - 131072) * 4; }
            else if (r < 262144) { src = wo; dst = wob;           e = (r - 196608) * 4; }
            else if (r < 262272) { src = bq; dst = bcat;          e = (r - 262144) * 4; }
            else if (r < 262400) { src = bk; dst = bcat + 512;    e = (r - 262272) * 4; }
            else if (r < 262528) { src = bv; dst = bcat + 1024;   e = (r - 262400) * 4; }
            else                 { src = bo; dst = bob;           e = (r - 262528) * 4; }
        }
        float4 v = *(const float4*)(src + e);
        union { bf16 h[4]; uint2 u; } cv;
        cv.h[0] = (bf16)v.x; cv.h[1] = (bf16)v.y;
        cv.h[2] = (bf16)v.z; cv.h[3] = (bf16)v.w;
        *(uint2*)(dst + e) = cv.u;
    }
    {
        const unsigned int* mw32 = (const unsigned int*)mask;
        int lane = tid & 63;
        int hit = 0;
#pragma unroll
        for (int i = 0; i < 8; ++i) {
            unsigned int w = mw32[lane + i * 64];
            if (w > 1u && (w & 0xFEFEFEFEu) == 0u) hit = 1;
        }
        const bool isbyte = (__ballot(hit) != 0ull);
        int wid  = (b * 256 + tid) >> 6;
        int nwav = (2048 * 256) >> 6;
        int total = (S / 64) * S;
        for (int w = wid; w < total; w += nwav) {
            int word = w >> 12;          // 0..63
            int row  = w & (S - 1);      // 0..4095
            int col  = word * 64 + lane;
            unsigned int v;
            if (isbyte) v = ((const unsigned char*)mask)[(size_t)row * MROW + col];
            else        v = ((const unsigned int*)mask)[(size_t)row * MROW + col];
            unsigned long long bb = __ballot(v != 0u);
            if (lane == 0) bitsT[(size_t)word * S + row] = bb;
        }
    }
}

// ---------------------------------------------------------------------------
// QKV GEMM: C(64x64 tile) = A(Mx512) @ W^T + bias, N=1536 fused (r3-best).
// out planar Q|K|V, each [h][s][64] bf16; Q pre-scaled by CMUL.
// ---------------------------------------------------------------------------
__global__ __launch_bounds__(256) void gemm_qkv(const bf16* __restrict__ A,
                                                const bf16* __restrict__ W,
                                                const bf16* __restrict__ bias,
                                                bf16* __restrict__ out)
{
    __shared__ bf16 As[64][72];
    __shared__ bf16 Bs[64][72];
    const int tid  = threadIdx.x;
    const int wid  = tid >> 6, lane = tid & 63;
    const int quad = lane >> 4, l15 = lane & 15;
    const int nbase = blockIdx.x * 64;
    const int mbase = blockIdx.y * 64;
    const int m0 = wid * 16;

    f32x4 acc[4];
#pragma unroll
    for (int i = 0; i < 4; ++i) acc[i] = (f32x4){0.f, 0.f, 0.f, 0.f};

    for (int kt = 0; kt < E / 64; ++kt) {
        const int kb = kt * 64;
        __syncthreads();
#pragma unroll
        for (int i = 0; i < 2; ++i) {
            int slot = tid + i * 256;
            int row = slot >> 3, kg = slot & 7;
            *(uint4*)&As[row][kg * 8] = *(const uint4*)&A[(size_t)(mbase + row) * E + kb + kg * 8];
            *(uint4*)&Bs[row][kg * 8] = *(const uint4*)&W[(size_t)(nbase + row) * E + kb + kg * 8];
        }
        __syncthreads();
        bf16x8 a0 = *(bf16x8*)&As[m0 + l15][quad * 8];
        bf16x8 a1 = *(bf16x8*)&As[m0 + l15][32 + quad * 8];
#pragma unroll
        for (int nt = 0; nt < 4; ++nt) {
            bf16x8 b0 = *(bf16x8*)&Bs[nt * 16 + l15][quad * 8];
            bf16x8 b1 = *(bf16x8*)&Bs[nt * 16 + l15][32 + quad * 8];
            acc[nt] = __builtin_amdgcn_mfma_f32_16x16x32_bf16(a0, b0, acc[nt], 0, 0, 0);
            acc[nt] = __builtin_amdgcn_mfma_f32_16x16x32_bf16(a1, b1, acc[nt], 0, 0, 0);
        }
    }
#pragma unroll
    for (int nt = 0; nt < 4; ++nt) {
        int col = nbase + nt * 16 + l15;
        float bv = (float)bias[col];
#pragma unroll
        for (int r = 0; r < 4; ++r) {
            int row = mbase + m0 + quad * 4 + r;
            float v = acc[nt][r] + bv;
            int t = col >> 9, hh = (col >> 6) & 7, d = col & 63;
            if (t == 0) v *= CMUL;
            out[((size_t)t * H + hh) * S * D + (size_t)row * D + d] = (bf16)v;
        }
    }
}

// ---------------------------------------------------------------------------
// Fused flash attention, 8-WARP blocks (512 thr, 256 queries/block): K/V LDS
// staging amortizes over 2x queries vs r7 (1 K-uint4 + 4-dword V-perm per
// thread), LDS 49152 B -> 3 blocks/CU x 8 waves = 24 waves/CU (was 20).
// Per-warp body identical to r7: operand-swapped QK (P^T), RB pack-bias in
// QK C-init, sign-bit mask AND, v_perm pair-pack, half-tile pack||PV
// interleave. grid (S/256, H, 6) = 768 = exactly 3/CU. block 512.
// ---------------------------------------------------------------------------
__global__ __launch_bounds__(512, 6) void attn8(const bf16* __restrict__ Qp,
                                                const bf16* __restrict__ Kp,
                                                const bf16* __restrict__ Vp,
                                                const unsigned long long* __restrict__ bitsT,
                                                float* __restrict__ Opart,
                                                float* __restrict__ Lpart,
                                                int ktper)
{
    __shared__ __align__(16) char smem[49152];
    bf16 (*Ps)[32][64] = (bf16(*)[32][64])smem;             // 8 x 32q x 64t swizzled
    bf16 (*Ks)[64]     = (bf16(*)[64])(smem + 32768);       // 64x64 swizzled
    bf16 (*Vts)[64]    = (bf16(*)[64])(smem + 40960);       // 64x64 swizzled V^T

    const int tid  = threadIdx.x;
    const int wid  = tid >> 6, lane = tid & 63;
    const int quad = lane >> 4, l15 = lane & 15;
    const int qb = blockIdx.x, h = blockIdx.y, split = blockIdx.z;
    const int qbase = qb * 256;
    const int m0 = wid * 32;
    const bf16* Qh = Qp + (size_t)h * S * D;
    const bf16* Kh = Kp + (size_t)h * S * D;
    const bf16* Vh = Vp + (size_t)h * S * D;

    // staging maps for 512 threads: K one uint4/thread; V 4 dwords/thread
    const int krow0 = tid >> 3, kkg = tid & 7;
    const int ksw0 = (kkg ^ (krow0 & 7)) * 8;
    const int vt0 = (tid & 31) * 2, vd0 = (tid >> 5) * 4;   // vd0: 0..60 step 4

    // Q fragments direct from global: lane = query row (B-operand layout)
    const bf16* qr0 = Qh + (size_t)(qbase + m0 + l15) * D;
    bf16x8 aq00 = *(const bf16x8*)(qr0 + quad * 8);
    bf16x8 aq01 = *(const bf16x8*)(qr0 + 32 + quad * 8);
    bf16x8 aq10 = *(const bf16x8*)(qr0 + 16 * D + quad * 8);
    bf16x8 aq11 = *(const bf16x8*)(qr0 + 16 * D + 32 + quad * 8);

    // ones B-fragment for l-sum MFMA (col 0 only)
    bf16x8 bl;
    {
        union { short s; bf16 b; } one; one.b = (bf16)1.0f;
        short v = (l15 == 0) ? one.s : (short)0;
#pragma unroll
        for (int j = 0; j < 8; ++j) bl[j] = v;
    }

    f32x4 o[4][2];
#pragma unroll
    for (int dt = 0; dt < 4; ++dt)
#pragma unroll
        for (int u = 0; u < 2; ++u) o[dt][u] = (f32x4){0.f, 0.f, 0.f, 0.f};
    f32x4 accl[2];
    accl[0] = (f32x4){0.f, 0.f, 0.f, 0.f};
    accl[1] = (f32x4){0.f, 0.f, 0.f, 0.f};

    const int kt0 = split * ktper;
    const int kt1 = min(S / 64, kt0 + ktper);   // ragged tail

    const bf16* kp0 = Kh + (size_t)(kt0 * 64 + krow0) * D + kkg * 8;
    const bf16* vp0 = Vh + (size_t)(kt0 * 64 + vt0) * D + vd0;
    const bf16* vp1 = Vh + (size_t)(kt0 * 64 + vt0 + 1) * D + vd0;
    uint4 kq0 = *(const uint4*)kp0;
    uint2 vq0 = *(const uint2*)vp0;
    uint2 vq1 = *(const uint2*)vp1;

    const unsigned long long* mb0 = bitsT + (size_t)kt0 * S + qbase + m0 + l15;
    const unsigned long long* mb1 = mb0 + 16;

    const int ksw_rd = (l15 & 7);
    const float RB = 0.002816949f;              // log2(1+2^-9): pack-round bias
#pragma unroll 1
    for (int kt = kt0; kt < kt1; ++kt) {
        __syncthreads();   // previous tile consumed
        *(uint4*)&Ks[krow0][ksw0] = kq0;
        {
            const unsigned int* w0 = (const unsigned int*)&vq0;
            const unsigned int* w1 = (const unsigned int*)&vq1;
#pragma unroll
            for (int j = 0; j < 4; ++j) {
                unsigned int pk = __builtin_amdgcn_perm(
                    w1[j >> 1], w0[j >> 1],
                    (j & 1) ? 0x07060302u : 0x05040100u);
                // swizzle key = (d & 7) * 8, d = vd0 + j, vd0 % 8 in {0,4}
                *(unsigned int*)&Vts[vd0 + j][vt0 ^ ((((vd0 & 4) + j) & 7) * 8)] = pk;
            }
        }
        if (kt + 1 < kt1) {
            kp0 += 64 * D; vp0 += 64 * D; vp1 += 64 * D;
            kq0 = *(const uint4*)kp0;
            vq0 = *(const uint2*)vp0;
            vq1 = *(const uint2*)vp1;
        }
        unsigned long long mw0 = *mb0; mb0 += S;
        unsigned long long mw1 = *mb1; mb1 += S;
        __syncthreads();   // K/V tile visible

        // S^T = K Q^T (exp2 domain, C-init = RB)
        f32x4 sc[2][4];
        {
            f32x4 z = (f32x4){RB, RB, RB, RB};
            __builtin_amdgcn_s_setprio(1);
#pragma unroll
            for (int nt = 0; nt < 4; ++nt) {
                bf16x8 kb0 = *(bf16x8*)&Ks[nt * 16 + l15][(quad ^ ksw_rd) * 8];
                bf16x8 kb1 = *(bf16x8*)&Ks[nt * 16 + l15][((quad + 4) ^ ksw_rd) * 8];
                sc[0][nt] = __builtin_amdgcn_mfma_f32_16x16x32_bf16(kb0, aq00, z, 0, 0, 0);
                sc[0][nt] = __builtin_amdgcn_mfma_f32_16x16x32_bf16(kb1, aq01, sc[0][nt], 0, 0, 0);
                sc[1][nt] = __builtin_amdgcn_mfma_f32_16x16x32_bf16(kb0, aq10, z, 0, 0, 0);
                sc[1][nt] = __builtin_amdgcn_mfma_f32_16x16x32_bf16(kb1, aq11, sc[1][nt], 0, 0, 0);
            }
            __builtin_amdgcn_s_setprio(0);
        }
        // Half-tile interleave: pack(nt01) -> PV slice 0 || pack(nt23) -> PV1
#pragma unroll
        for (int half = 0; half < 2; ++half) {
#pragma unroll
            for (int u = 0; u < 2; ++u) {
                const unsigned long long sh = (u ? mw1 : mw0) >> (quad * 4);
                const unsigned int wlo = (unsigned int)sh;
                const unsigned int whi = (unsigned int)(sh >> 32);
#pragma unroll
                for (int ntl = 0; ntl < 2; ++ntl) {
                    const int nt = half * 2 + ntl;
                    const unsigned int wsel = (nt < 2) ? wlo : whi;
                    unsigned int a[4];
#pragma unroll
                    for (int r = 0; r < 4; ++r) {
                        const int bit = (nt & 1) * 16 + r;
                        unsigned int m = (unsigned int)((int)(wsel << (31 - bit)) >> 31);
                        a[r] = __float_as_uint(__builtin_amdgcn_exp2f(sc[u][nt][r])) & m;
                    }
                    uint2 pk;
                    pk.x = __builtin_amdgcn_perm(a[1], a[0], 0x07060302u);
                    pk.y = __builtin_amdgcn_perm(a[3], a[2], 0x07060302u);
                    *(uint2*)&Ps[wid][u * 16 + l15][(nt * 16 + quad * 4) ^ (ksw_rd * 8)] = pk;
                }
            }
            const int cu = ((quad + half * 4) ^ ksw_rd) * 8;
            bf16x8 ap0 = *(bf16x8*)&Ps[wid][l15][(quad * 8 + half * 32) ^ (ksw_rd * 8)];
            bf16x8 ap1 = *(bf16x8*)&Ps[wid][16 + l15][(quad * 8 + half * 32) ^ (ksw_rd * 8)];
            __builtin_amdgcn_s_setprio(1);
            accl[0] = __builtin_amdgcn_mfma_f32_16x16x32_bf16(ap0, bl, accl[0], 0, 0, 0);
            accl[1] = __builtin_amdgcn_mfma_f32_16x16x32_bf16(ap1, bl, accl[1], 0, 0, 0);
#pragma unroll
            for (int dt = 0; dt < 4; ++dt) {
                bf16x8 bv = *(bf16x8*)&Vts[dt * 16 + l15][cu];
                o[dt][0] = __builtin_amdgcn_mfma_f32_16x16x32_bf16(ap0, bv, o[dt][0], 0, 0, 0);
                o[dt][1] = __builtin_amdgcn_mfma_f32_16x16x32_bf16(ap1, bv, o[dt][1], 0, 0, 0);
            }
            __builtin_amdgcn_s_setprio(0);
        }
    }
    // epilogue: fp32 partials
    float* Op = Opart + (size_t)(split * H + h) * S * D;
    float* Lp = Lpart + (size_t)(split * H + h) * S;
#pragma unroll
    for (int u = 0; u < 2; ++u)
#pragma unroll
        for (int r = 0; r < 4; ++r) {
            int row = qbase + m0 + u * 16 + quad * 4 + r;
            if (l15 == 0) Lp[row] = accl[u][r];
#pragma unroll
            for (int dt = 0; dt < 4; ++dt)
                Op[(size_t)row * D + dt * 16 + l15] = o[dt][u][r];
        }
}

// ---------------------------------------------------------------------------
// Fused flash attention, r7 4-warp fallback (ws < 76 MB). 32 q/warp,
// LDS 32768 -> 5 blocks/CU with nsplit=5. grid (S/128, H, nsplit), blk 256.
// ---------------------------------------------------------------------------
__global__ __launch_bounds__(256) void attn(const bf16* __restrict__ Qp,
                                            const bf16* __restrict__ Kp,
                                            const bf16* __restrict__ Vp,
                                            const unsigned long long* __restrict__ bitsT,
                                            float* __restrict__ Opart,
                                            float* __restrict__ Lpart,
                                            int ktper)
{
    __shared__ __align__(16) char smem[32768];
    bf16 (*Ps)[32][64] = (bf16(*)[32][64])smem;
    bf16 (*Ks)[64]     = (bf16(*)[64])(smem + 16384);
    bf16 (*Vts)[64]    = (bf16(*)[64])(smem + 24576);

    const int tid  = threadIdx.x;
    const int wid  = tid >> 6, lane = tid & 63;
    const int quad = lane >> 4, l15 = lane & 15;
    const int qb = blockIdx.x, h = blockIdx.y, split = blockIdx.z;
    const int qbase = qb * 128;
    const int m0 = wid * 32;
    const bf16* Qh = Qp + (size_t)h * S * D;
    const bf16* Kh = Kp + (size_t)h * S * D;
    const bf16* Vh = Vp + (size_t)h * S * D;

    const int krow0 = tid >> 3, kkg = tid & 7;
    const int krow1 = (tid + 256) >> 3;
    const int ksw0 = (kkg ^ (krow0 & 7)) * 8;
    const int ksw1 = (kkg ^ (krow1 & 7)) * 8;
    const int vt0 = (tid & 31) * 2, vd0 = (tid >> 5) * 8;

    const bf16* qr0 = Qh + (size_t)(qbase + m0 + l15) * D;
    bf16x8 aq00 = *(const bf16x8*)(qr0 + quad * 8);
    bf16x8 aq01 = *(const bf16x8*)(qr0 + 32 + quad * 8);
    bf16x8 aq10 = *(const bf16x8*)(qr0 + 16 * D + quad * 8);
    bf16x8 aq11 = *(const bf16x8*)(qr0 + 16 * D + 32 + quad * 8);

    bf16x8 bl;
    {
        union { short s; bf16 b; } one; one.b = (bf16)1.0f;
        short v = (l15 == 0) ? one.s : (short)0;
#pragma unroll
        for (int j = 0; j < 8; ++j) bl[j] = v;
    }

    f32x4 o[4][2];
#pragma unroll
    for (int dt = 0; dt < 4; ++dt)
#pragma unroll
        for (int u = 0; u < 2; ++u) o[dt][u] = (f32x4){0.f, 0.f, 0.f, 0.f};
    f32x4 accl[2];
    accl[0] = (f32x4){0.f, 0.f, 0.f, 0.f};
    accl[1] = (f32x4){0.f, 0.f, 0.f, 0.f};

    const int kt0 = split * ktper;
    const int kt1 = min(S / 64, kt0 + ktper);

    const bf16* kp0 = Kh + (size_t)(kt0 * 64 + krow0) * D + kkg * 8;
    const bf16* kp1 = Kh + (size_t)(kt0 * 64 + krow1) * D + kkg * 8;
    const bf16* vp0 = Vh + (size_t)(kt0 * 64 + vt0) * D + vd0;
    const bf16* vp1 = Vh + (size_t)(kt0 * 64 + vt0 + 1) * D + vd0;
    uint4 kq0 = *(const uint4*)kp0;
    uint4 kq1 = *(const uint4*)kp1;
    uint4 vq0 = *(const uint4*)vp0;
    uint4 vq1 = *(const uint4*)vp1;

    const unsigned long long* mb0 = bitsT + (size_t)kt0 * S + qbase + m0 + l15;
    const unsigned long long* mb1 = mb0 + 16;

    const int ksw_rd = (l15 & 7);
    const float RB = 0.002816949f;
#pragma unroll 1
    for (int kt = kt0; kt < kt1; ++kt) {
        __syncthreads();
        *(uint4*)&Ks[krow0][ksw0] = kq0;
        *(uint4*)&Ks[krow1][ksw1] = kq1;
        {
            const unsigned int* w0 = (const unsigned int*)&vq0;
            const unsigned int* w1 = (const unsigned int*)&vq1;
#pragma unroll
            for (int j = 0; j < 8; ++j) {
                unsigned int pk = __builtin_amdgcn_perm(
                    w1[j >> 1], w0[j >> 1],
                    (j & 1) ? 0x07060302u : 0x05040100u);
                *(unsigned int*)&Vts[vd0 + j][vt0 ^ (j * 8)] = pk;
            }
        }
        if (kt + 1 < kt1) {
            kp0 += 64 * D; kp1 += 64 * D; vp0 += 64 * D; vp1 += 64 * D;
            kq0 = *(const uint4*)kp0;
            kq1 = *(const uint4*)kp1;
            vq0 = *(const uint4*)vp0;
            vq1 = *(const uint4*)vp1;
        }
        unsigned long long mw0 = *mb0; mb0 += S;
        unsigned long long mw1 = *mb1; mb1 += S;
        __syncthreads();

        f32x4 sc[2][4];
        {
            f32x4 z = (f32x4){RB, RB, RB, RB};
            __builtin_amdgcn_s_setprio(1);
#pragma unroll
            for (int nt = 0; nt < 4; ++nt) {
                bf16x8 kb0 = *(bf16x8*)&Ks[nt * 16 + l15][(quad ^ ksw_rd) * 8];
                bf16x8 kb1 = *(bf16x8*)&Ks[nt * 16 + l15][((quad + 4) ^ ksw_rd) * 8];
                sc[0][nt] = __builtin_amdgcn_mfma_f32_16x16x32_bf16(kb0, aq00, z, 0, 0, 0);
                sc[0][nt] = __builtin_amdgcn_mfma_f32_16x16x32_bf16(kb1, aq01, sc[0][nt], 0, 0, 0);
                sc[1][nt] = __builtin_amdgcn_mfma_f32_16x16x32_bf16(kb0, aq10, z, 0, 0, 0);
                sc[1][nt] = __builtin_amdgcn_mfma_f32_16x16x32_bf16(kb1, aq11, sc[1][nt], 0, 0, 0);
            }
            __builtin_amdgcn_s_setprio(0);
        }
#pragma unroll
        for (int half = 0; half < 2; ++half) {
#pragma unroll
            for (int u = 0; u < 2; ++u) {
                const unsigned long long sh = (u ? mw1 : mw0) >> (quad * 4);
                const unsigned int wlo = (unsigned int)sh;
                const unsigned int whi = (unsigned int)(sh >> 32);
#pragma unroll
                for (int ntl = 0; ntl < 2; ++ntl) {
                    const int nt = half * 2 + ntl;
                    const unsigned int wsel = (nt < 2) ? wlo : whi;
                    unsigned int a[4];
#pragma unroll
                    for (int r = 0; r < 4; ++r) {
                        const int bit = (nt & 1) * 16 + r;
                        unsigned int m = (unsigned int)((int)(wsel << (31 - bit)) >> 31);
                        a[r] = __float_as_uint(__builtin_amdgcn_exp2f(sc[u][nt][r])) & m;
                    }
                    uint2 pk;
                    pk.x = __builtin_amdgcn_perm(a[1], a[0], 0x07060302u);
                    pk.y = __builtin_amdgcn_perm(a[3], a[2], 0x07060302u);
                    *(uint2*)&Ps[wid][u * 16 + l15][(nt * 16 + quad * 4) ^ (ksw_rd * 8)] = pk;
                }
            }
            const int cu = ((quad + half * 4) ^ ksw_rd) * 8;
            bf16x8 ap0 = *(bf16x8*)&Ps[wid][l15][(quad * 8 + half * 32) ^ (ksw_rd * 8)];
            bf16x8 ap1 = *(bf16x8*)&Ps[wid][16 + l15][(quad * 8 + half * 32) ^ (ksw_rd * 8)];
            __builtin_amdgcn_s_setprio(1);
            accl[0] = __builtin_amdgcn_mfma_f32_16x16x32_bf16(ap0, bl, accl[0], 0, 0, 0);
            accl[1] = __builtin_amdgcn_mfma_f32_16x16x32_bf16(ap1, bl, accl[1], 0, 0, 0);
#pragma unroll
            for (int dt = 0; dt < 4; ++dt) {
                bf16x8 bv = *(bf16x8*)&Vts[dt * 16 + l15][cu];
                o[dt][0] = __builtin_amdgcn_mfma_f32_16x16x32_bf16(ap0, bv, o[dt][0], 0, 0, 0);
                o[dt][1] = __builtin_amdgcn_mfma_f32_16x16x32_bf16(ap1, bv, o[dt][1], 0, 0, 0);
            }
            __builtin_amdgcn_s_setprio(0);
        }
    }
    float* Op = Opart + (size_t)(split * H + h) * S * D;
    float* Lp = Lpart + (size_t)(split * H + h) * S;
#pragma unroll
    for (int u = 0; u < 2; ++u)
#pragma unroll
        for (int r = 0; r < 4; ++r) {
            int row = qbase + m0 + u * 16 + quad * 4 + r;
            if (l15 == 0) Lp[row] = accl[u][r];
#pragma unroll
            for (int dt = 0; dt < 4; ++dt)
                Op[(size_t)row * D + dt * 16 + l15] = o[dt][u][r];
        }
}

// ---------------------------------------------------------------------------
// combine: one-pass K-split reduction + l-normalization + bf16 cast.
// ---------------------------------------------------------------------------
__global__ __launch_bounds__(256) void combine(const float* __restrict__ Opart,
                                               const float* __restrict__ Lpart,
                                               bf16* __restrict__ Ab, int nsplit)
{
    const size_t oh = (size_t)H * S * D;
    int g = blockIdx.x * 256 + threadIdx.x;       // 262144 threads = S*E/8
    int row = g >> 6;
    int cg  = g & 63;
    int hh  = cg >> 3;
    int d0  = (cg & 7) * 8;
    size_t base = ((size_t)hh * S + row) * D + d0;
    float a[8] = {0.f, 0.f, 0.f, 0.f, 0.f, 0.f, 0.f, 0.f};
    float l = 0.f;
    for (int s = 0; s < nsplit; ++s) {
        float4 p0 = *(const float4*)(Opart + (size_t)s * oh + base);
        float4 p1 = *(const float4*)(Opart + (size_t)s * oh + base + 4);
        a[0] += p0.x; a[1] += p0.y; a[2] += p0.z; a[3] += p0.w;
        a[4] += p1.x; a[5] += p1.y; a[6] += p1.z; a[7] += p1.w;
        l += Lpart[(size_t)s * H * S + (size_t)hh * S + row];
    }
    float inv = (l > 0.f) ? 1.f / l : 0.f;
    union { bf16 hb[8]; uint4 u; } cv;
#pragma unroll
    for (int j = 0; j < 8; ++j) cv.hb[j] = (bf16)(a[j] * inv);
    *(uint4*)&Ab[(size_t)row * E + hh * 64 + d0] = cv.u;
}

// ---------------------------------------------------------------------------
// Output GEMM (r3-best 64x64): out = Ab @ Wo^T + bo, fp32. grid (8, 64).
// ---------------------------------------------------------------------------
__global__ __launch_bounds__(256) void gemm_out(const bf16* __restrict__ A,
                                                const bf16* __restrict__ W,
                                                const bf16* __restrict__ bias,
                                                float* __restrict__ out)
{
    __shared__ bf16 As[64][72];
    __shared__ bf16 Bs[64][72];
    const int tid  = threadIdx.x;
    const int wid  = tid >> 6, lane = tid & 63;
    const int quad = lane >> 4, l15 = lane & 15;
    const int nbase = blockIdx.x * 64;
    const int mbase = blockIdx.y * 64;
    const int m0 = wid * 16;

    f32x4 acc[4];
#pragma unroll
    for (int i = 0; i < 4; ++i) acc[i] = (f32x4){0.f, 0.f, 0.f, 0.f};

    for (int kt = 0; kt < E / 64; ++kt) {
        const int kb = kt * 64;
        __syncthreads();
#pragma unroll
        for (int i = 0; i < 2; ++i) {
            int slot = tid + i * 256;
            int row = slot >> 3, kg = slot & 7;
            *(uint4*)&As[row][kg * 8] = *(const uint4*)&A[(size_t)(mbase + row) * E + kb + kg * 8];
            *(uint4*)&Bs[row][kg * 8] = *(const uint4*)&W[(size_t)(nbase + row) * E + kb + kg * 8];
        }
        __syncthreads();
        bf16x8 a0 = *(bf16x8*)&As[m0 + l15][quad * 8];
        bf16x8 a1 = *(bf16x8*)&As[m0 + l15][32 + quad * 8];
#pragma unroll
        for (int nt = 0; nt < 4; ++nt) {
            bf16x8 b0 = *(bf16x8*)&Bs[nt * 16 + l15][quad * 8];
            bf16x8 b1 = *(bf16x8*)&Bs[nt * 16 + l15][32 + quad * 8];
            acc[nt] = __builtin_amdgcn_mfma_f32_16x16x32_bf16(a0, b0, acc[nt], 0, 0, 0);
            acc[nt] = __builtin_amdgcn_mfma_f32_16x16x32_bf16(a1, b1, acc[nt], 0, 0, 0);
        }
    }
#pragma unroll
    for (int nt = 0; nt < 4; ++nt) {
        int col = nbase + nt * 16 + l15;
        float bv = (float)bias[col];
#pragma unroll
        for (int r = 0; r < 4; ++r) {
            int row = mbase + m0 + quad * 4 + r;
            out[(size_t)row * E + col] = acc[nt][r] + bv;
        }
    }
}

// ---------------------------------------------------------------------------
extern "C" void kernel_launch(void* const* d_in, const int* in_sizes, int n_in,
                              void* d_out, int out_size, void* d_ws, size_t ws_size,
                              hipStream_t stream)
{
    char* ws = (char*)d_ws;
    const size_t MB = (size_t)1 << 20;
    bf16* Qw   = (bf16*)(ws + 0 * MB);        // 12 MB: Q|K|V planar cat
    bf16* Kw   = (bf16*)(ws + 4 * MB);
    bf16* Vw   = (bf16*)(ws + 8 * MB);
    bf16* Ab   = (bf16*)(ws + 12 * MB);       // 4 MB combined attn out (bf16)
    unsigned long long* bitsT = (unsigned long long*)(ws + 16 * MB); // 2 MB
    bf16* xb   = (bf16*)(ws + 18 * MB);       // 4 MB
    bf16* Wcat = (bf16*)(ws + 22 * MB);       // 1.5 MB
    bf16* Wob  = (bf16*)(ws + 24 * MB);       // 0.5 MB
    bf16* bcat = (bf16*)(ws + 25 * MB);
    bf16* bob  = (bf16*)(ws + 25 * MB + 8192);
    float* Opart = (float*)(ws + 26 * MB);    // nsplit x 8 MB

    // wide path: 8-warp attn, nsplit=6, grid 768 = 3 blocks/CU balanced.
    const bool wide = (ws_size >= 76 * MB);
    int nsplit = wide ? 6 : (ws_size >= 68 * MB) ? 5 : (ws_size >= 59 * MB) ? 4 : 2;
    int ktper  = (S / 64 + nsplit - 1) / nsplit;
    float* Lpart = (float*)(ws + 26 * MB + (size_t)nsplit * 8 * MB);

    hipLaunchKernelGGL(prep, dim3(2048), dim3(256), 0, stream,
                       d_in[9], bitsT,
                       (const float*)d_in[0], (const float*)d_in[1],
                       (const float*)d_in[3], (const float*)d_in[5],
                       (const float*)d_in[7], (const float*)d_in[2],
                       (const float*)d_in[4], (const float*)d_in[6],
                       (const float*)d_in[8],
                       xb, Wcat, Wob, bcat, bob);
    hipLaunchKernelGGL(gemm_qkv, dim3(24, 64), dim3(256), 0, stream,
                       xb, Wcat, bcat, Qw);
    if (wide)
        hipLaunchKernelGGL(attn8, dim3(S / 256, H, nsplit), dim3(512), 0, stream,
                           Qw, Kw, Vw, bitsT, Opart, Lpart, ktper);
    else
        hipLaunchKernelGGL(attn, dim3(S / 128, H, nsplit), dim3(256), 0, stream,
                           Qw, Kw, Vw, bitsT, Opart, Lpart, ktper);
    hipLaunchKernelGGL(combine, dim3(1024), dim3(256), 0, stream,
                       Opart, Lpart, Ab, nsplit);
    hipLaunchKernelGGL(gemm_out, dim3(8, 64), dim3(256), 0, stream,
                       Ab, Wob, bob, (float*)d_out);
}

// Round 9
// 268.431 us; speedup vs baseline: 1.9039x; 1.9039x over previous
//
#include <hip/hip_runtime.h>
#include <hip/hip_bf16.h>
#include <stdint.h>

#define S 4096
#define E 512
#define H 8
#define D 64
#define MROW 5000        // mask row stride (MAX_GENES)

typedef __hip_bfloat16 bf16;
typedef __attribute__((ext_vector_type(8))) short bf16x8;
typedef __attribute__((ext_vector_type(4))) float f32x4;

#define CMUL (0.125f * 1.4426950408889634f)  // scale * log2(e), folded into Q

// ---------------------------------------------------------------------------
// prep: all 2048 blocks convert fp32->bf16 (12 MB) via branch-structured
// segment select, then pack mask into TRANSPOSED bit matrix bitsT[word][row].
// ---------------------------------------------------------------------------
__global__ __launch_bounds__(256) void prep(
    const void* __restrict__ mask, unsigned long long* __restrict__ bitsT,
    const float* __restrict__ x,  const float* __restrict__ wq,
    const float* __restrict__ wk, const float* __restrict__ wv,
    const float* __restrict__ wo, const float* __restrict__ bq,
    const float* __restrict__ bk, const float* __restrict__ bv,
    const float* __restrict__ bo,
    bf16* __restrict__ xb, bf16* __restrict__ wcat, bf16* __restrict__ wob,
    bf16* __restrict__ bcat, bf16* __restrict__ bob)
{
    const int tid = threadIdx.x;
    const int b   = blockIdx.x;
    const int gid = b * 256 + tid;
    for (int g = gid; g < 786944; g += 524288) {
        const float* src; bf16* dst; int e;
        if (g < 524288) { src = x; dst = xb; e = g * 4; }
        else {
            int r = g - 524288;
            if      (r < 65536)  { src = wq; dst = wcat;          e = r * 4; }
            else if (r < 131072) { src = wk; dst = wcat + 262144; e = (r - 65536) * 4; }
            else if (r < 196608) { src = wv; dst = wcat + 524288; e = (r - 131072) * 4; }
            else if (r < 262144) { src = wo; dst = wob;           e = (r - 196608) * 4; }
            else if (r < 262272) { src = bq; dst = bcat;          e = (r - 262144) * 4; }
            else if (r < 262400) { src = bk; dst = bcat + 512;    e = (r - 262272) * 4; }
            else if (r < 262528) { src = bv; dst = bcat + 1024;   e = (r - 262400) * 4; }
            else                 { src = bo; dst = bob;           e = (r - 262528) * 4; }
        }
        float4 v = *(const float4*)(src + e);
        union { bf16 h[4]; uint2 u; } cv;
        cv.h[0] = (bf16)v.x; cv.h[1] = (bf16)v.y;
        cv.h[2] = (bf16)v.z; cv.h[3] = (bf16)v.w;
        *(uint2*)(dst + e) = cv.u;
    }
    {
        const unsigned int* mw32 = (const unsigned int*)mask;
        int lane = tid & 63;
        int hit = 0;
#pragma unroll
        for (int i = 0; i < 8; ++i) {
            unsigned int w = mw32[lane + i * 64];
            if (w > 1u && (w & 0xFEFEFEFEu) == 0u) hit = 1;
        }
        const bool isbyte = (__ballot(hit) != 0ull);
        int wid  = (b * 256 + tid) >> 6;
        int nwav = (2048 * 256) >> 6;
        int total = (S / 64) * S;
        for (int w = wid; w < total; w += nwav) {
            int word = w >> 12;          // 0..63
            int row  = w & (S - 1);      // 0..4095
            int col  = word * 64 + lane;
            unsigned int v;
            if (isbyte) v = ((const unsigned char*)mask)[(size_t)row * MROW + col];
            else        v = ((const unsigned int*)mask)[(size_t)row * MROW + col];
            unsigned long long bb = __ballot(v != 0u);
            if (lane == 0) bitsT[(size_t)word * S + row] = bb;
        }
    }
}

// ---------------------------------------------------------------------------
// QKV GEMM: C(64x64 tile) = A(Mx512) @ W^T + bias, N=1536 fused (r3-best).
// out planar Q|K|V, each [h][s][64] bf16; Q pre-scaled by CMUL.
// ---------------------------------------------------------------------------
__global__ __launch_bounds__(256) void gemm_qkv(const bf16* __restrict__ A,
                                                const bf16* __restrict__ W,
                                                const bf16* __restrict__ bias,
                                                bf16* __restrict__ out)
{
    __shared__ bf16 As[64][72];
    __shared__ bf16 Bs[64][72];
    const int tid  = threadIdx.x;
    const int wid  = tid >> 6, lane = tid & 63;
    const int quad = lane >> 4, l15 = lane & 15;
    const int nbase = blockIdx.x * 64;
    const int mbase = blockIdx.y * 64;
    const int m0 = wid * 16;

    f32x4 acc[4];
#pragma unroll
    for (int i = 0; i < 4; ++i) acc[i] = (f32x4){0.f, 0.f, 0.f, 0.f};

    for (int kt = 0; kt < E / 64; ++kt) {
        const int kb = kt * 64;
        __syncthreads();
#pragma unroll
        for (int i = 0; i < 2; ++i) {
            int slot = tid + i * 256;
            int row = slot >> 3, kg = slot & 7;
            *(uint4*)&As[row][kg * 8] = *(const uint4*)&A[(size_t)(mbase + row) * E + kb + kg * 8];
            *(uint4*)&Bs[row][kg * 8] = *(const uint4*)&W[(size_t)(nbase + row) * E + kb + kg * 8];
        }
        __syncthreads();
        bf16x8 a0 = *(bf16x8*)&As[m0 + l15][quad * 8];
        bf16x8 a1 = *(bf16x8*)&As[m0 + l15][32 + quad * 8];
#pragma unroll
        for (int nt = 0; nt < 4; ++nt) {
            bf16x8 b0 = *(bf16x8*)&Bs[nt * 16 + l15][quad * 8];
            bf16x8 b1 = *(bf16x8*)&Bs[nt * 16 + l15][32 + quad * 8];
            acc[nt] = __builtin_amdgcn_mfma_f32_16x16x32_bf16(a0, b0, acc[nt], 0, 0, 0);
            acc[nt] = __builtin_amdgcn_mfma_f32_16x16x32_bf16(a1, b1, acc[nt], 0, 0, 0);
        }
    }
#pragma unroll
    for (int nt = 0; nt < 4; ++nt) {
        int col = nbase + nt * 16 + l15;
        float bv = (float)bias[col];
#pragma unroll
        for (int r = 0; r < 4; ++r) {
            int row = mbase + m0 + quad * 4 + r;
            float v = acc[nt][r] + bv;
            int t = col >> 9, hh = (col >> 6) & 7, d = col & 63;
            if (t == 0) v *= CMUL;
            out[((size_t)t * H + hh) * S * D + (size_t)row * D + d] = (bf16)v;
        }
    }
}

// ---------------------------------------------------------------------------
// Fused flash attention, 8-WARP blocks (512 thr, 256 queries/block).
// r8's __launch_bounds__(512, 6) demanded 6 waves/EU => <=85 VGPR/wave; the
// allocator missed by a few regs and spilled ALL accumulator state to
// scratch (VGPR_Count 40, 1.4 GB HBM/dispatch). Fix: plain
// __launch_bounds__(512) — compiler allocates ~90 VGPR; occupancy is then
// LDS-bound at 49152 B -> 3 blocks/CU x 8 waves = 24 waves/CU (the target).
// Per-warp body identical to r7. grid (S/256, H, 6) = 768 = 3/CU. block 512.
// ---------------------------------------------------------------------------
__global__ __launch_bounds__(512) void attn8(const bf16* __restrict__ Qp,
                                             const bf16* __restrict__ Kp,
                                             const bf16* __restrict__ Vp,
                                             const unsigned long long* __restrict__ bitsT,
                                             float* __restrict__ Opart,
                                             float* __restrict__ Lpart,
                                             int ktper)
{
    __shared__ __align__(16) char smem[49152];
    bf16 (*Ps)[32][64] = (bf16(*)[32][64])smem;             // 8 x 32q x 64t swizzled
    bf16 (*Ks)[64]     = (bf16(*)[64])(smem + 32768);       // 64x64 swizzled
    bf16 (*Vts)[64]    = (bf16(*)[64])(smem + 40960);       // 64x64 swizzled V^T

    const int tid  = threadIdx.x;
    const int wid  = tid >> 6, lane = tid & 63;
    const int quad = lane >> 4, l15 = lane & 15;
    const int qb = blockIdx.x, h = blockIdx.y, split = blockIdx.z;
    const int qbase = qb * 256;
    const int m0 = wid * 32;
    const bf16* Qh = Qp + (size_t)h * S * D;
    const bf16* Kh = Kp + (size_t)h * S * D;
    const bf16* Vh = Vp + (size_t)h * S * D;

    // staging maps for 512 threads: K one uint4/thread; V 4 dwords/thread
    const int krow0 = tid >> 3, kkg = tid & 7;
    const int ksw0 = (kkg ^ (krow0 & 7)) * 8;
    const int vt0 = (tid & 31) * 2, vd0 = (tid >> 5) * 4;   // vd0: 0..60 step 4

    // Q fragments direct from global: lane = query row (B-operand layout)
    const bf16* qr0 = Qh + (size_t)(qbase + m0 + l15) * D;
    bf16x8 aq00 = *(const bf16x8*)(qr0 + quad * 8);
    bf16x8 aq01 = *(const bf16x8*)(qr0 + 32 + quad * 8);
    bf16x8 aq10 = *(const bf16x8*)(qr0 + 16 * D + quad * 8);
    bf16x8 aq11 = *(const bf16x8*)(qr0 + 16 * D + 32 + quad * 8);

    // ones B-fragment for l-sum MFMA (col 0 only)
    bf16x8 bl;
    {
        union { short s; bf16 b; } one; one.b = (bf16)1.0f;
        short v = (l15 == 0) ? one.s : (short)0;
#pragma unroll
        for (int j = 0; j < 8; ++j) bl[j] = v;
    }

    f32x4 o[4][2];
#pragma unroll
    for (int dt = 0; dt < 4; ++dt)
#pragma unroll
        for (int u = 0; u < 2; ++u) o[dt][u] = (f32x4){0.f, 0.f, 0.f, 0.f};
    f32x4 accl[2];
    accl[0] = (f32x4){0.f, 0.f, 0.f, 0.f};
    accl[1] = (f32x4){0.f, 0.f, 0.f, 0.f};

    const int kt0 = split * ktper;
    const int kt1 = min(S / 64, kt0 + ktper);   // ragged tail

    const bf16* kp0 = Kh + (size_t)(kt0 * 64 + krow0) * D + kkg * 8;
    const bf16* vp0 = Vh + (size_t)(kt0 * 64 + vt0) * D + vd0;
    const bf16* vp1 = Vh + (size_t)(kt0 * 64 + vt0 + 1) * D + vd0;
    uint4 kq0 = *(const uint4*)kp0;
    uint2 vq0 = *(const uint2*)vp0;
    uint2 vq1 = *(const uint2*)vp1;

    const unsigned long long* mb0 = bitsT + (size_t)kt0 * S + qbase + m0 + l15;
    const unsigned long long* mb1 = mb0 + 16;

    const int ksw_rd = (l15 & 7);
    const float RB = 0.002816949f;              // log2(1+2^-9): pack-round bias
#pragma unroll 1
    for (int kt = kt0; kt < kt1; ++kt) {
        __syncthreads();   // previous tile consumed
        *(uint4*)&Ks[krow0][ksw0] = kq0;
        {
            const unsigned int* w0 = (const unsigned int*)&vq0;
            const unsigned int* w1 = (const unsigned int*)&vq1;
#pragma unroll
            for (int j = 0; j < 4; ++j) {
                unsigned int pk = __builtin_amdgcn_perm(
                    w1[j >> 1], w0[j >> 1],
                    (j & 1) ? 0x07060302u : 0x05040100u);
                // swizzle key = (d & 7) * 8, d = vd0 + j, vd0 % 8 in {0,4}
                *(unsigned int*)&Vts[vd0 + j][vt0 ^ ((((vd0 & 4) + j) & 7) * 8)] = pk;
            }
        }
        if (kt + 1 < kt1) {
            kp0 += 64 * D; vp0 += 64 * D; vp1 += 64 * D;
            kq0 = *(const uint4*)kp0;
            vq0 = *(const uint2*)vp0;
            vq1 = *(const uint2*)vp1;
        }
        unsigned long long mw0 = *mb0; mb0 += S;
        unsigned long long mw1 = *mb1; mb1 += S;
        __syncthreads();   // K/V tile visible

        // S^T = K Q^T (exp2 domain, C-init = RB)
        f32x4 sc[2][4];
        {
            f32x4 z = (f32x4){RB, RB, RB, RB};
            __builtin_amdgcn_s_setprio(1);
#pragma unroll
            for (int nt = 0; nt < 4; ++nt) {
                bf16x8 kb0 = *(bf16x8*)&Ks[nt * 16 + l15][(quad ^ ksw_rd) * 8];
                bf16x8 kb1 = *(bf16x8*)&Ks[nt * 16 + l15][((quad + 4) ^ ksw_rd) * 8];
                sc[0][nt] = __builtin_amdgcn_mfma_f32_16x16x32_bf16(kb0, aq00, z, 0, 0, 0);
                sc[0][nt] = __builtin_amdgcn_mfma_f32_16x16x32_bf16(kb1, aq01, sc[0][nt], 0, 0, 0);
                sc[1][nt] = __builtin_amdgcn_mfma_f32_16x16x32_bf16(kb0, aq10, z, 0, 0, 0);
                sc[1][nt] = __builtin_amdgcn_mfma_f32_16x16x32_bf16(kb1, aq11, sc[1][nt], 0, 0, 0);
            }
            __builtin_amdgcn_s_setprio(0);
        }
        // Half-tile interleave: pack(nt01) -> PV slice 0 || pack(nt23) -> PV1
#pragma unroll
        for (int half = 0; half < 2; ++half) {
#pragma unroll
            for (int u = 0; u < 2; ++u) {
                const unsigned long long sh = (u ? mw1 : mw0) >> (quad * 4);
                const unsigned int wlo = (unsigned int)sh;
                const unsigned int whi = (unsigned int)(sh >> 32);
#pragma unroll
                for (int ntl = 0; ntl < 2; ++ntl) {
                    const int nt = half * 2 + ntl;
                    const unsigned int wsel = (nt < 2) ? wlo : whi;
                    unsigned int a[4];
#pragma unroll
                    for (int r = 0; r < 4; ++r) {
                        const int bit = (nt & 1) * 16 + r;
                        unsigned int m = (unsigned int)((int)(wsel << (31 - bit)) >> 31);
                        a[r] = __float_as_uint(__builtin_amdgcn_exp2f(sc[u][nt][r])) & m;
                    }
                    uint2 pk;
                    pk.x = __builtin_amdgcn_perm(a[1], a[0], 0x07060302u);
                    pk.y = __builtin_amdgcn_perm(a[3], a[2], 0x07060302u);
                    *(uint2*)&Ps[wid][u * 16 + l15][(nt * 16 + quad * 4) ^ (ksw_rd * 8)] = pk;
                }
            }
            const int cu = ((quad + half * 4) ^ ksw_rd) * 8;
            bf16x8 ap0 = *(bf16x8*)&Ps[wid][l15][(quad * 8 + half * 32) ^ (ksw_rd * 8)];
            bf16x8 ap1 = *(bf16x8*)&Ps[wid][16 + l15][(quad * 8 + half * 32) ^ (ksw_rd * 8)];
            __builtin_amdgcn_s_setprio(1);
            accl[0] = __builtin_amdgcn_mfma_f32_16x16x32_bf16(ap0, bl, accl[0], 0, 0, 0);
            accl[1] = __builtin_amdgcn_mfma_f32_16x16x32_bf16(ap1, bl, accl[1], 0, 0, 0);
#pragma unroll
            for (int dt = 0; dt < 4; ++dt) {
                bf16x8 bv = *(bf16x8*)&Vts[dt * 16 + l15][cu];
                o[dt][0] = __builtin_amdgcn_mfma_f32_16x16x32_bf16(ap0, bv, o[dt][0], 0, 0, 0);
                o[dt][1] = __builtin_amdgcn_mfma_f32_16x16x32_bf16(ap1, bv, o[dt][1], 0, 0, 0);
            }
            __builtin_amdgcn_s_setprio(0);
        }
    }
    // epilogue: fp32 partials
    float* Op = Opart + (size_t)(split * H + h) * S * D;
    float* Lp = Lpart + (size_t)(split * H + h) * S;
#pragma unroll
    for (int u = 0; u < 2; ++u)
#pragma unroll
        for (int r = 0; r < 4; ++r) {
            int row = qbase + m0 + u * 16 + quad * 4 + r;
            if (l15 == 0) Lp[row] = accl[u][r];
#pragma unroll
            for (int dt = 0; dt < 4; ++dt)
                Op[(size_t)row * D + dt * 16 + l15] = o[dt][u][r];
        }
}

// ---------------------------------------------------------------------------
// Fused flash attention, r7 4-warp fallback (ws < 76 MB). 32 q/warp,
// LDS 32768 -> 5 blocks/CU with nsplit=5. grid (S/128, H, nsplit), blk 256.
// ---------------------------------------------------------------------------
__global__ __launch_bounds__(256) void attn(const bf16* __restrict__ Qp,
                                            const bf16* __restrict__ Kp,
                                            const bf16* __restrict__ Vp,
                                            const unsigned long long* __restrict__ bitsT,
                                            float* __restrict__ Opart,
                                            float* __restrict__ Lpart,
                                            int ktper)
{
    __shared__ __align__(16) char smem[32768];
    bf16 (*Ps)[32][64] = (bf16(*)[32][64])smem;
    bf16 (*Ks)[64]     = (bf16(*)[64])(smem + 16384);
    bf16 (*Vts)[64]    = (bf16(*)[64])(smem + 24576);

    const int tid  = threadIdx.x;
    const int wid  = tid >> 6, lane = tid & 63;
    const int quad = lane >> 4, l15 = lane & 15;
    const int qb = blockIdx.x, h = blockIdx.y, split = blockIdx.z;
    const int qbase = qb * 128;
    const int m0 = wid * 32;
    const bf16* Qh = Qp + (size_t)h * S * D;
    const bf16* Kh = Kp + (size_t)h * S * D;
    const bf16* Vh = Vp + (size_t)h * S * D;

    const int krow0 = tid >> 3, kkg = tid & 7;
    const int krow1 = (tid + 256) >> 3;
    const int ksw0 = (kkg ^ (krow0 & 7)) * 8;
    const int ksw1 = (kkg ^ (krow1 & 7)) * 8;
    const int vt0 = (tid & 31) * 2, vd0 = (tid >> 5) * 8;

    const bf16* qr0 = Qh + (size_t)(qbase + m0 + l15) * D;
    bf16x8 aq00 = *(const bf16x8*)(qr0 + quad * 8);
    bf16x8 aq01 = *(const bf16x8*)(qr0 + 32 + quad * 8);
    bf16x8 aq10 = *(const bf16x8*)(qr0 + 16 * D + quad * 8);
    bf16x8 aq11 = *(const bf16x8*)(qr0 + 16 * D + 32 + quad * 8);

    bf16x8 bl;
    {
        union { short s; bf16 b; } one; one.b = (bf16)1.0f;
        short v = (l15 == 0) ? one.s : (short)0;
#pragma unroll
        for (int j = 0; j < 8; ++j) bl[j] = v;
    }

    f32x4 o[4][2];
#pragma unroll
    for (int dt = 0; dt < 4; ++dt)
#pragma unroll
        for (int u = 0; u < 2; ++u) o[dt][u] = (f32x4){0.f, 0.f, 0.f, 0.f};
    f32x4 accl[2];
    accl[0] = (f32x4){0.f, 0.f, 0.f, 0.f};
    accl[1] = (f32x4){0.f, 0.f, 0.f, 0.f};

    const int kt0 = split * ktper;
    const int kt1 = min(S / 64, kt0 + ktper);

    const bf16* kp0 = Kh + (size_t)(kt0 * 64 + krow0) * D + kkg * 8;
    const bf16* kp1 = Kh + (size_t)(kt0 * 64 + krow1) * D + kkg * 8;
    const bf16* vp0 = Vh + (size_t)(kt0 * 64 + vt0) * D + vd0;
    const bf16* vp1 = Vh + (size_t)(kt0 * 64 + vt0 + 1) * D + vd0;
    uint4 kq0 = *(const uint4*)kp0;
    uint4 kq1 = *(const uint4*)kp1;
    uint4 vq0 = *(const uint4*)vp0;
    uint4 vq1 = *(const uint4*)vp1;

    const unsigned long long* mb0 = bitsT + (size_t)kt0 * S + qbase + m0 + l15;
    const unsigned long long* mb1 = mb0 + 16;

    const int ksw_rd = (l15 & 7);
    const float RB = 0.002816949f;
#pragma unroll 1
    for (int kt = kt0; kt < kt1; ++kt) {
        __syncthreads();
        *(uint4*)&Ks[krow0][ksw0] = kq0;
        *(uint4*)&Ks[krow1][ksw1] = kq1;
        {
            const unsigned int* w0 = (const unsigned int*)&vq0;
            const unsigned int* w1 = (const unsigned int*)&vq1;
#pragma unroll
            for (int j = 0; j < 8; ++j) {
                unsigned int pk = __builtin_amdgcn_perm(
                    w1[j >> 1], w0[j >> 1],
                    (j & 1) ? 0x07060302u : 0x05040100u);
                *(unsigned int*)&Vts[vd0 + j][vt0 ^ (j * 8)] = pk;
            }
        }
        if (kt + 1 < kt1) {
            kp0 += 64 * D; kp1 += 64 * D; vp0 += 64 * D; vp1 += 64 * D;
            kq0 = *(const uint4*)kp0;
            kq1 = *(const uint4*)kp1;
            vq0 = *(const uint4*)vp0;
            vq1 = *(const uint4*)vp1;
        }
        unsigned long long mw0 = *mb0; mb0 += S;
        unsigned long long mw1 = *mb1; mb1 += S;
        __syncthreads();

        f32x4 sc[2][4];
        {
            f32x4 z = (f32x4){RB, RB, RB, RB};
            __builtin_amdgcn_s_setprio(1);
#pragma unroll
            for (int nt = 0; nt < 4; ++nt) {
                bf16x8 kb0 = *(bf16x8*)&Ks[nt * 16 + l15][(quad ^ ksw_rd) * 8];
                bf16x8 kb1 = *(bf16x8*)&Ks[nt * 16 + l15][((quad + 4) ^ ksw_rd) * 8];
                sc[0][nt] = __builtin_amdgcn_mfma_f32_16x16x32_bf16(kb0, aq00, z, 0, 0, 0);
                sc[0][nt] = __builtin_amdgcn_mfma_f32_16x16x32_bf16(kb1, aq01, sc[0][nt], 0, 0, 0);
                sc[1][nt] = __builtin_amdgcn_mfma_f32_16x16x32_bf16(kb0, aq10, z, 0, 0, 0);
                sc[1][nt] = __builtin_amdgcn_mfma_f32_16x16x32_bf16(kb1, aq11, sc[1][nt], 0, 0, 0);
            }
            __builtin_amdgcn_s_setprio(0);
        }
#pragma unroll
        for (int half = 0; half < 2; ++half) {
#pragma unroll
            for (int u = 0; u < 2; ++u) {
                const unsigned long long sh = (u ? mw1 : mw0) >> (quad * 4);
                const unsigned int wlo = (unsigned int)sh;
                const unsigned int whi = (unsigned int)(sh >> 32);
#pragma unroll
                for (int ntl = 0; ntl < 2; ++ntl) {
                    const int nt = half * 2 + ntl;
                    const unsigned int wsel = (nt < 2) ? wlo : whi;
                    unsigned int a[4];
#pragma unroll
                    for (int r = 0; r < 4; ++r) {
                        const int bit = (nt & 1) * 16 + r;
                        unsigned int m = (unsigned int)((int)(wsel << (31 - bit)) >> 31);
                        a[r] = __float_as_uint(__builtin_amdgcn_exp2f(sc[u][nt][r])) & m;
                    }
                    uint2 pk;
                    pk.x = __builtin_amdgcn_perm(a[1], a[0], 0x07060302u);
                    pk.y = __builtin_amdgcn_perm(a[3], a[2], 0x07060302u);
                    *(uint2*)&Ps[wid][u * 16 + l15][(nt * 16 + quad * 4) ^ (ksw_rd * 8)] = pk;
                }
            }
            const int cu = ((quad + half * 4) ^ ksw_rd) * 8;
            bf16x8 ap0 = *(bf16x8*)&Ps[wid][l15][(quad * 8 + half * 32) ^ (ksw_rd * 8)];
            bf16x8 ap1 = *(bf16x8*)&Ps[wid][16 + l15][(quad * 8 + half * 32) ^ (ksw_rd * 8)];
            __builtin_amdgcn_s_setprio(1);
            accl[0] = __builtin_amdgcn_mfma_f32_16x16x32_bf16(ap0, bl, accl[0], 0, 0, 0);
            accl[1] = __builtin_amdgcn_mfma_f32_16x16x32_bf16(ap1, bl, accl[1], 0, 0, 0);
#pragma unroll
            for (int dt = 0; dt < 4; ++dt) {
                bf16x8 bv = *(bf16x8*)&Vts[dt * 16 + l15][cu];
                o[dt][0] = __builtin_amdgcn_mfma_f32_16x16x32_bf16(ap0, bv, o[dt][0], 0, 0, 0);
                o[dt][1] = __builtin_amdgcn_mfma_f32_16x16x32_bf16(ap1, bv, o[dt][1], 0, 0, 0);
            }
            __builtin_amdgcn_s_setprio(0);
        }
    }
    float* Op = Opart + (size_t)(split * H + h) * S * D;
    float* Lp = Lpart + (size_t)(split * H + h) * S;
#pragma unroll
    for (int u = 0; u < 2; ++u)
#pragma unroll
        for (int r = 0; r < 4; ++r) {
            int row = qbase + m0 + u * 16 + quad * 4 + r;
            if (l15 == 0) Lp[row] = accl[u][r];
#pragma unroll
            for (int dt = 0; dt < 4; ++dt)
                Op[(size_t)row * D + dt * 16 + l15] = o[dt][u][r];
        }
}

// ---------------------------------------------------------------------------
// combine: one-pass K-split reduction + l-normalization + bf16 cast.
// ---------------------------------------------------------------------------
__global__ __launch_bounds__(256) void combine(const float* __restrict__ Opart,
                                               const float* __restrict__ Lpart,
                                               bf16* __restrict__ Ab, int nsplit)
{
    const size_t oh = (size_t)H * S * D;
    int g = blockIdx.x * 256 + threadIdx.x;       // 262144 threads = S*E/8
    int row = g >> 6;
    int cg  = g & 63;
    int hh  = cg >> 3;
    int d0  = (cg & 7) * 8;
    size_t base = ((size_t)hh * S + row) * D + d0;
    float a[8] = {0.f, 0.f, 0.f, 0.f, 0.f, 0.f, 0.f, 0.f};
    float l = 0.f;
    for (int s = 0; s < nsplit; ++s) {
        float4 p0 = *(const float4*)(Opart + (size_t)s * oh + base);
        float4 p1 = *(const float4*)(Opart + (size_t)s * oh + base + 4);
        a[0] += p0.x; a[1] += p0.y; a[2] += p0.z; a[3] += p0.w;
        a[4] += p1.x; a[5] += p1.y; a[6] += p1.z; a[7] += p1.w;
        l += Lpart[(size_t)s * H * S + (size_t)hh * S + row];
    }
    float inv = (l > 0.f) ? 1.f / l : 0.f;
    union { bf16 hb[8]; uint4 u; } cv;
#pragma unroll
    for (int j = 0; j < 8; ++j) cv.hb[j] = (bf16)(a[j] * inv);
    *(uint4*)&Ab[(size_t)row * E + hh * 64 + d0] = cv.u;
}

// ---------------------------------------------------------------------------
// Output GEMM (r3-best 64x64): out = Ab @ Wo^T + bo, fp32. grid (8, 64).
// ---------------------------------------------------------------------------
__global__ __launch_bounds__(256) void gemm_out(const bf16* __restrict__ A,
                                                const bf16* __restrict__ W,
                                                const bf16* __restrict__ bias,
                                                float* __restrict__ out)
{
    __shared__ bf16 As[64][72];
    __shared__ bf16 Bs[64][72];
    const int tid  = threadIdx.x;
    const int wid  = tid >> 6, lane = tid & 63;
    const int quad = lane >> 4, l15 = lane & 15;
    const int nbase = blockIdx.x * 64;
    const int mbase = blockIdx.y * 64;
    const int m0 = wid * 16;

    f32x4 acc[4];
#pragma unroll
    for (int i = 0; i < 4; ++i) acc[i] = (f32x4){0.f, 0.f, 0.f, 0.f};

    for (int kt = 0; kt < E / 64; ++kt) {
        const int kb = kt * 64;
        __syncthreads();
#pragma unroll
        for (int i = 0; i < 2; ++i) {
            int slot = tid + i * 256;
            int row = slot >> 3, kg = slot & 7;
            *(uint4*)&As[row][kg * 8] = *(const uint4*)&A[(size_t)(mbase + row) * E + kb + kg * 8];
            *(uint4*)&Bs[row][kg * 8] = *(const uint4*)&W[(size_t)(nbase + row) * E + kb + kg * 8];
        }
        __syncthreads();
        bf16x8 a0 = *(bf16x8*)&As[m0 + l15][quad * 8];
        bf16x8 a1 = *(bf16x8*)&As[m0 + l15][32 + quad * 8];
#pragma unroll
        for (int nt = 0; nt < 4; ++nt) {
            bf16x8 b0 = *(bf16x8*)&Bs[nt * 16 + l15][quad * 8];
            bf16x8 b1 = *(bf16x8*)&Bs[nt * 16 + l15][32 + quad * 8];
            acc[nt] = __builtin_amdgcn_mfma_f32_16x16x32_bf16(a0, b0, acc[nt], 0, 0, 0);
            acc[nt] = __builtin_amdgcn_mfma_f32_16x16x32_bf16(a1, b1, acc[nt], 0, 0, 0);
        }
    }
#pragma unroll
    for (int nt = 0; nt < 4; ++nt) {
        int col = nbase + nt * 16 + l15;
        float bv = (float)bias[col];
#pragma unroll
        for (int r = 0; r < 4; ++r) {
            int row = mbase + m0 + quad * 4 + r;
            out[(size_t)row * E + col] = acc[nt][r] + bv;
        }
    }
}

// ---------------------------------------------------------------------------
extern "C" void kernel_launch(void* const* d_in, const int* in_sizes, int n_in,
                              void* d_out, int out_size, void* d_ws, size_t ws_size,
                              hipStream_t stream)
{
    char* ws = (char*)d_ws;
    const size_t MB = (size_t)1 << 20;
    bf16* Qw   = (bf16*)(ws + 0 * MB);        // 12 MB: Q|K|V planar cat
    bf16* Kw   = (bf16*)(ws + 4 * MB);
    bf16* Vw   = (bf16*)(ws + 8 * MB);
    bf16* Ab   = (bf16*)(ws + 12 * MB);       // 4 MB combined attn out (bf16)
    unsigned long long* bitsT = (unsigned long long*)(ws + 16 * MB); // 2 MB
    bf16* xb   = (bf16*)(ws + 18 * MB);       // 4 MB
    bf16* Wcat = (bf16*)(ws + 22 * MB);       // 1.5 MB
    bf16* Wob  = (bf16*)(ws + 24 * MB);       // 0.5 MB
    bf16* bcat = (bf16*)(ws + 25 * MB);
    bf16* bob  = (bf16*)(ws + 25 * MB + 8192);
    float* Opart = (float*)(ws + 26 * MB);    // nsplit x 8 MB

    // wide path: 8-warp attn, nsplit=6, grid 768 = 3 blocks/CU balanced.
    const bool wide = (ws_size >= 76 * MB);
    int nsplit = wide ? 6 : (ws_size >= 68 * MB) ? 5 : (ws_size >= 59 * MB) ? 4 : 2;
    int ktper  = (S / 64 + nsplit - 1) / nsplit;
    float* Lpart = (float*)(ws + 26 * MB + (size_t)nsplit * 8 * MB);

    hipLaunchKernelGGL(prep, dim3(2048), dim3(256), 0, stream,
                       d_in[9], bitsT,
                       (const float*)d_in[0], (const float*)d_in[1],
                       (const float*)d_in[3], (const float*)d_in[5],
                       (const float*)d_in[7], (const float*)d_in[2],
                       (const float*)d_in[4], (const float*)d_in[6],
                       (const float*)d_in[8],
                       xb, Wcat, Wob, bcat, bob);
    hipLaunchKernelGGL(gemm_qkv, dim3(24, 64), dim3(256), 0, stream,
                       xb, Wcat, bcat, Qw);
    if (wide)
        hipLaunchKernelGGL(attn8, dim3(S / 256, H, nsplit), dim3(512), 0, stream,
                           Qw, Kw, Vw, bitsT, Opart, Lpart, ktper);
    else
        hipLaunchKernelGGL(attn, dim3(S / 128, H, nsplit), dim3(256), 0, stream,
                           Qw, Kw, Vw, bitsT, Opart, Lpart, ktper);
    hipLaunchKernelGGL(combine, dim3(1024), dim3(256), 0, stream,
                       Opart, Lpart, Ab, nsplit);
    hipLaunchKernelGGL(gemm_out, dim3(8, 64), dim3(256), 0, stream,
                       Ab, Wob, bob, (float*)d_out);
}

// Round 11
// 255.511 us; speedup vs baseline: 2.0002x; 1.0506x over previous
//
#include <hip/hip_runtime.h>
#include <hip/hip_bf16.h>
#include <stdint.h>

#define S 4096
#define E 512
#define H 8
#define D 64
#define MROW 5000        // mask row stride (MAX_GENES)

typedef __hip_bfloat16 bf16;
typedef __attribute__((ext_vector_type(8))) short bf16x8;
typedef __attribute__((ext_vector_type(4))) float f32x4;

#define CMUL (0.125f * 1.4426950408889634f)  // scale * log2(e), folded into Q

// ---------------------------------------------------------------------------
// prep: all 2048 blocks convert fp32->bf16 (12 MB) via branch-structured
// segment select, then pack mask into TRANSPOSED bit matrix bitsT[word][row].
// ---------------------------------------------------------------------------
__global__ __launch_bounds__(256) void prep(
    const void* __restrict__ mask, unsigned long long* __restrict__ bitsT,
    const float* __restrict__ x,  const float* __restrict__ wq,
    const float* __restrict__ wk, const float* __restrict__ wv,
    const float* __restrict__ wo, const float* __restrict__ bq,
    const float* __restrict__ bk, const float* __restrict__ bv,
    const float* __restrict__ bo,
    bf16* __restrict__ xb, bf16* __restrict__ wcat, bf16* __restrict__ wob,
    bf16* __restrict__ bcat, bf16* __restrict__ bob)
{
    const int tid = threadIdx.x;
    const int b   = blockIdx.x;
    const int gid = b * 256 + tid;
    for (int g = gid; g < 786944; g += 524288) {
        const float* src; bf16* dst; int e;
        if (g < 524288) { src = x; dst = xb; e = g * 4; }
        else {
            int r = g - 524288;
            if      (r < 65536)  { src = wq; dst = wcat;          e = r * 4; }
            else if (r < 131072) { src = wk; dst = wcat + 262144; e = (r - 65536) * 4; }
            else if (r < 196608) { src = wv; dst = wcat + 524288; e = (r - 131072) * 4; }
            else if (r < 262144) { src = wo; dst = wob;           e = (r - 196608) * 4; }
            else if (r < 262272) { src = bq; dst = bcat;          e = (r - 262144) * 4; }
            else if (r < 262400) { src = bk; dst = bcat + 512;    e = (r - 262272) * 4; }
            else if (r < 262528) { src = bv; dst = bcat + 1024;   e = (r - 262400) * 4; }
            else                 { src = bo; dst = bob;           e = (r - 262528) * 4; }
        }
        float4 v = *(const float4*)(src + e);
        union { bf16 h[4]; uint2 u; } cv;
        cv.h[0] = (bf16)v.x; cv.h[1] = (bf16)v.y;
        cv.h[2] = (bf16)v.z; cv.h[3] = (bf16)v.w;
        *(uint2*)(dst + e) = cv.u;
    }
    {
        const unsigned int* mw32 = (const unsigned int*)mask;
        int lane = tid & 63;
        int hit = 0;
#pragma unroll
        for (int i = 0; i < 8; ++i) {
            unsigned int w = mw32[lane + i * 64];
            if (w > 1u && (w & 0xFEFEFEFEu) == 0u) hit = 1;
        }
        const bool isbyte = (__ballot(hit) != 0ull);
        int wid  = (b * 256 + tid) >> 6;
        int nwav = (2048 * 256) >> 6;
        int total = (S / 64) * S;
        for (int w = wid; w < total; w += nwav) {
            int word = w >> 12;          // 0..63
            int row  = w & (S - 1);      // 0..4095
            int col  = word * 64 + lane;
            unsigned int v;
            if (isbyte) v = ((const unsigned char*)mask)[(size_t)row * MROW + col];
            else        v = ((const unsigned int*)mask)[(size_t)row * MROW + col];
            unsigned long long bb = __ballot(v != 0u);
            if (lane == 0) bitsT[(size_t)word * S + row] = bb;
        }
    }
}

// ---------------------------------------------------------------------------
// QKV GEMM: C(64x64 tile) = A(Mx512) @ W^T + bias, N=1536 fused (r3-best).
// out planar Q|K|V, each [h][s][64] bf16; Q pre-scaled by CMUL.
// ---------------------------------------------------------------------------
__global__ __launch_bounds__(256) void gemm_qkv(const bf16* __restrict__ A,
                                                const bf16* __restrict__ W,
                                                const bf16* __restrict__ bias,
                                                bf16* __restrict__ out)
{
    __shared__ bf16 As[64][72];
    __shared__ bf16 Bs[64][72];
    const int tid  = threadIdx.x;
    const int wid  = tid >> 6, lane = tid & 63;
    const int quad = lane >> 4, l15 = lane & 15;
    const int nbase = blockIdx.x * 64;
    const int mbase = blockIdx.y * 64;
    const int m0 = wid * 16;

    f32x4 acc[4];
#pragma unroll
    for (int i = 0; i < 4; ++i) acc[i] = (f32x4){0.f, 0.f, 0.f, 0.f};

    for (int kt = 0; kt < E / 64; ++kt) {
        const int kb = kt * 64;
        __syncthreads();
#pragma unroll
        for (int i = 0; i < 2; ++i) {
            int slot = tid + i * 256;
            int row = slot >> 3, kg = slot & 7;
            *(uint4*)&As[row][kg * 8] = *(const uint4*)&A[(size_t)(mbase + row) * E + kb + kg * 8];
            *(uint4*)&Bs[row][kg * 8] = *(const uint4*)&W[(size_t)(nbase + row) * E + kb + kg * 8];
        }
        __syncthreads();
        bf16x8 a0 = *(bf16x8*)&As[m0 + l15][quad * 8];
        bf16x8 a1 = *(bf16x8*)&As[m0 + l15][32 + quad * 8];
#pragma unroll
        for (int nt = 0; nt < 4; ++nt) {
            bf16x8 b0 = *(bf16x8*)&Bs[nt * 16 + l15][quad * 8];
            bf16x8 b1 = *(bf16x8*)&Bs[nt * 16 + l15][32 + quad * 8];
            acc[nt] = __builtin_amdgcn_mfma_f32_16x16x32_bf16(a0, b0, acc[nt], 0, 0, 0);
            acc[nt] = __builtin_amdgcn_mfma_f32_16x16x32_bf16(a1, b1, acc[nt], 0, 0, 0);
        }
    }
#pragma unroll
    for (int nt = 0; nt < 4; ++nt) {
        int col = nbase + nt * 16 + l15;
        float bv = (float)bias[col];
#pragma unroll
        for (int r = 0; r < 4; ++r) {
            int row = mbase + m0 + quad * 4 + r;
            float v = acc[nt][r] + bv;
            int t = col >> 9, hh = (col >> 6) & 7, d = col & 63;
            if (t == 0) v *= CMUL;
            out[((size_t)t * H + hh) * S * D + (size_t)row * D + d] = (bf16)v;
        }
    }
}

// ---------------------------------------------------------------------------
// Fused flash attention, 32 queries/warp (128/block). Operand-swapped QK
// (P^T layout), pack-round bias folded into QK C-init (RB = log2(1+2^-9)),
// sign-bit mask AND, v_perm pair-pack, half-tile pack||PV interleave
// (QK -> pack01 -> PV slice 0 -> pack23 -> PV slice 1: slice-1 pack VALU
// issues under slice-0 MFMAs). LDS=32768 -> 5 blocks/CU with nsplit=5.
// Measured best: 61 us. grid (S/128, H, nsplit), block 256.
// ---------------------------------------------------------------------------
__global__ __launch_bounds__(256) void attn(const bf16* __restrict__ Qp,
                                            const bf16* __restrict__ Kp,
                                            const bf16* __restrict__ Vp,
                                            const unsigned long long* __restrict__ bitsT,
                                            float* __restrict__ Opart,
                                            float* __restrict__ Lpart,
                                            int ktper)
{
    __shared__ __align__(16) char smem[32768];
    bf16 (*Ps)[32][64] = (bf16(*)[32][64])smem;             // 4 x 32q x 64t swizzled
    bf16 (*Ks)[64]     = (bf16(*)[64])(smem + 16384);       // 64x64 swizzled
    bf16 (*Vts)[64]    = (bf16(*)[64])(smem + 24576);       // 64x64 swizzled V^T

    const int tid  = threadIdx.x;
    const int wid  = tid >> 6, lane = tid & 63;
    const int quad = lane >> 4, l15 = lane & 15;
    const int qb = blockIdx.x, h = blockIdx.y, split = blockIdx.z;
    const int qbase = qb * 128;
    const int m0 = wid * 32;
    const bf16* Qh = Qp + (size_t)h * S * D;
    const bf16* Kh = Kp + (size_t)h * S * D;
    const bf16* Vh = Vp + (size_t)h * S * D;

    const int krow0 = tid >> 3, kkg = tid & 7;
    const int krow1 = (tid + 256) >> 3;
    const int ksw0 = (kkg ^ (krow0 & 7)) * 8;
    const int ksw1 = (kkg ^ (krow1 & 7)) * 8;
    const int vt0 = (tid & 31) * 2, vd0 = (tid >> 5) * 8;

    // Q fragments direct from global: lane = query row (B-operand layout);
    // two query sub-tiles per warp (u=0: rows m0+l15, u=1: rows m0+16+l15)
    const bf16* qr0 = Qh + (size_t)(qbase + m0 + l15) * D;
    bf16x8 aq00 = *(const bf16x8*)(qr0 + quad * 8);
    bf16x8 aq01 = *(const bf16x8*)(qr0 + 32 + quad * 8);
    bf16x8 aq10 = *(const bf16x8*)(qr0 + 16 * D + quad * 8);
    bf16x8 aq11 = *(const bf16x8*)(qr0 + 16 * D + 32 + quad * 8);

    // ones B-fragment for l-sum MFMA (col 0 only)
    bf16x8 bl;
    {
        union { short s; bf16 b; } one; one.b = (bf16)1.0f;
        short v = (l15 == 0) ? one.s : (short)0;
#pragma unroll
        for (int j = 0; j < 8; ++j) bl[j] = v;
    }

    f32x4 o[4][2];
#pragma unroll
    for (int dt = 0; dt < 4; ++dt)
#pragma unroll
        for (int u = 0; u < 2; ++u) o[dt][u] = (f32x4){0.f, 0.f, 0.f, 0.f};
    f32x4 accl[2];
    accl[0] = (f32x4){0.f, 0.f, 0.f, 0.f};
    accl[1] = (f32x4){0.f, 0.f, 0.f, 0.f};

    const int kt0 = split * ktper;
    const int kt1 = min(S / 64, kt0 + ktper);   // ragged tail for nsplit=5

    // strength-reduced prefetch pointers: advance by one K-tile (64*D) per kt
    const bf16* kp0 = Kh + (size_t)(kt0 * 64 + krow0) * D + kkg * 8;
    const bf16* kp1 = Kh + (size_t)(kt0 * 64 + krow1) * D + kkg * 8;
    const bf16* vp0 = Vh + (size_t)(kt0 * 64 + vt0) * D + vd0;
    const bf16* vp1 = Vh + (size_t)(kt0 * 64 + vt0 + 1) * D + vd0;
    uint4 kq0 = *(const uint4*)kp0;
    uint4 kq1 = *(const uint4*)kp1;
    uint4 vq0 = *(const uint4*)vp0;
    uint4 vq1 = *(const uint4*)vp1;

    // transposed mask: one 8B word per lane per query sub-tile, coalesced
    const unsigned long long* mb0 = bitsT + (size_t)kt0 * S + qbase + m0 + l15;
    const unsigned long long* mb1 = mb0 + 16;

    const int ksw_rd = (l15 & 7);               // K/V/P read-write swizzle key
    const float RB = 0.002816949f;              // log2(1+2^-9): pack-round bias
#pragma unroll 1
    for (int kt = kt0; kt < kt1; ++kt) {
        __syncthreads();   // previous tile consumed
        *(uint4*)&Ks[krow0][ksw0] = kq0;
        *(uint4*)&Ks[krow1][ksw1] = kq1;
        {
            const unsigned int* w0 = (const unsigned int*)&vq0;
            const unsigned int* w1 = (const unsigned int*)&vq1;
#pragma unroll
            for (int j = 0; j < 8; ++j) {
                unsigned int pk = __builtin_amdgcn_perm(
                    w1[j >> 1], w0[j >> 1],
                    (j & 1) ? 0x07060302u : 0x05040100u);
                *(unsigned int*)&Vts[vd0 + j][vt0 ^ (j * 8)] = pk;
            }
        }
        if (kt + 1 < kt1) {
            kp0 += 64 * D; kp1 += 64 * D; vp0 += 64 * D; vp1 += 64 * D;
            kq0 = *(const uint4*)kp0;
            kq1 = *(const uint4*)kp1;
            vq0 = *(const uint4*)vp0;
            vq1 = *(const uint4*)vp1;
        }
        unsigned long long mw0 = *mb0; mb0 += S;
        unsigned long long mw1 = *mb1; mb1 += S;
        __syncthreads();   // K/V tile visible

        // S^T = K Q^T (exp2 domain, C-init = RB): A = K frag, B = Q frag.
        f32x4 sc[2][4];
        {
            f32x4 z = (f32x4){RB, RB, RB, RB};
            __builtin_amdgcn_s_setprio(1);
#pragma unroll
            for (int nt = 0; nt < 4; ++nt) {
                bf16x8 kb0 = *(bf16x8*)&Ks[nt * 16 + l15][(quad ^ ksw_rd) * 8];
                bf16x8 kb1 = *(bf16x8*)&Ks[nt * 16 + l15][((quad + 4) ^ ksw_rd) * 8];
                sc[0][nt] = __builtin_amdgcn_mfma_f32_16x16x32_bf16(kb0, aq00, z, 0, 0, 0);
                sc[0][nt] = __builtin_amdgcn_mfma_f32_16x16x32_bf16(kb1, aq01, sc[0][nt], 0, 0, 0);
                sc[1][nt] = __builtin_amdgcn_mfma_f32_16x16x32_bf16(kb0, aq10, z, 0, 0, 0);
                sc[1][nt] = __builtin_amdgcn_mfma_f32_16x16x32_bf16(kb1, aq11, sc[1][nt], 0, 0, 0);
            }
            __builtin_amdgcn_s_setprio(0);
        }
        // Half-tile interleave: pack(nt=0,1) -> PV slice 0 || pack(nt=2,3)
        // -> PV slice 1. Pack: bits(exp2(sc)) & signext(bit) -> v_perm.
#pragma unroll
        for (int half = 0; half < 2; ++half) {
#pragma unroll
            for (int u = 0; u < 2; ++u) {
                const unsigned long long sh = (u ? mw1 : mw0) >> (quad * 4);
                const unsigned int wlo = (unsigned int)sh;
                const unsigned int whi = (unsigned int)(sh >> 32);
#pragma unroll
                for (int ntl = 0; ntl < 2; ++ntl) {
                    const int nt = half * 2 + ntl;
                    const unsigned int wsel = (nt < 2) ? wlo : whi;
                    unsigned int a[4];
#pragma unroll
                    for (int r = 0; r < 4; ++r) {
                        const int bit = (nt & 1) * 16 + r;     // compile-time
                        unsigned int m = (unsigned int)((int)(wsel << (31 - bit)) >> 31);
                        a[r] = __float_as_uint(__builtin_amdgcn_exp2f(sc[u][nt][r])) & m;
                    }
                    uint2 pk;
                    pk.x = __builtin_amdgcn_perm(a[1], a[0], 0x07060302u);
                    pk.y = __builtin_amdgcn_perm(a[3], a[2], 0x07060302u);
                    *(uint2*)&Ps[wid][u * 16 + l15][(nt * 16 + quad * 4) ^ (ksw_rd * 8)] = pk;
                }
            }
            // PV k-slice `half` (tokens half*32..+31): A-frags depend only on
            // the two nt groups just packed (XOR-swizzle-verified mapping).
            const int cu = ((quad + half * 4) ^ ksw_rd) * 8;
            bf16x8 ap0 = *(bf16x8*)&Ps[wid][l15][(quad * 8 + half * 32) ^ (ksw_rd * 8)];
            bf16x8 ap1 = *(bf16x8*)&Ps[wid][16 + l15][(quad * 8 + half * 32) ^ (ksw_rd * 8)];
            __builtin_amdgcn_s_setprio(1);
            accl[0] = __builtin_amdgcn_mfma_f32_16x16x32_bf16(ap0, bl, accl[0], 0, 0, 0);
            accl[1] = __builtin_amdgcn_mfma_f32_16x16x32_bf16(ap1, bl, accl[1], 0, 0, 0);
#pragma unroll
            for (int dt = 0; dt < 4; ++dt) {
                bf16x8 bv = *(bf16x8*)&Vts[dt * 16 + l15][cu];
                o[dt][0] = __builtin_amdgcn_mfma_f32_16x16x32_bf16(ap0, bv, o[dt][0], 0, 0, 0);
                o[dt][1] = __builtin_amdgcn_mfma_f32_16x16x32_bf16(ap1, bv, o[dt][1], 0, 0, 0);
            }
            __builtin_amdgcn_s_setprio(0);
        }
    }
    // epilogue: fp32 partials; O/l C-layout rows = u*16 + quad*4 + r
    float* Op = Opart + (size_t)(split * H + h) * S * D;
    float* Lp = Lpart + (size_t)(split * H + h) * S;
#pragma unroll
    for (int u = 0; u < 2; ++u)
#pragma unroll
        for (int r = 0; r < 4; ++r) {
            int row = qbase + m0 + u * 16 + quad * 4 + r;
            if (l15 == 0) Lp[row] = accl[u][r];
#pragma unroll
            for (int dt = 0; dt < 4; ++dt)
                Op[(size_t)row * D + dt * 16 + l15] = o[dt][u][r];
        }
}

// ---------------------------------------------------------------------------
// combine: one-pass K-split reduction + l-normalization + bf16 cast.
// Ab[row][c] = (sum_s Opart) / (sum_s L), c = h*64 + d.
// grid 1024, block 256: thread -> 8 contiguous cols of one row.
// ---------------------------------------------------------------------------
__global__ __launch_bounds__(256) void combine(const float* __restrict__ Opart,
                                               const float* __restrict__ Lpart,
                                               bf16* __restrict__ Ab, int nsplit)
{
    const size_t oh = (size_t)H * S * D;
    int g = blockIdx.x * 256 + threadIdx.x;       // 262144 threads = S*E/8
    int row = g >> 6;
    int cg  = g & 63;
    int hh  = cg >> 3;
    int d0  = (cg & 7) * 8;
    size_t base = ((size_t)hh * S + row) * D + d0;
    float a[8] = {0.f, 0.f, 0.f, 0.f, 0.f, 0.f, 0.f, 0.f};
    float l = 0.f;
    for (int s = 0; s < nsplit; ++s) {
        float4 p0 = *(const float4*)(Opart + (size_t)s * oh + base);
        float4 p1 = *(const float4*)(Opart + (size_t)s * oh + base + 4);
        a[0] += p0.x; a[1] += p0.y; a[2] += p0.z; a[3] += p0.w;
        a[4] += p1.x; a[5] += p1.y; a[6] += p1.z; a[7] += p1.w;
        l += Lpart[(size_t)s * H * S + (size_t)hh * S + row];
    }
    float inv = (l > 0.f) ? 1.f / l : 0.f;
    union { bf16 hb[8]; uint4 u; } cv;
#pragma unroll
    for (int j = 0; j < 8; ++j) cv.hb[j] = (bf16)(a[j] * inv);
    *(uint4*)&Ab[(size_t)row * E + hh * 64 + d0] = cv.u;
}

// ---------------------------------------------------------------------------
// Output GEMM (r3-best 64x64): out = Ab @ Wo^T + bo, fp32. grid (8, 64).
// ---------------------------------------------------------------------------
__global__ __launch_bounds__(256) void gemm_out(const bf16* __restrict__ A,
                                                const bf16* __restrict__ W,
                                                const bf16* __restrict__ bias,
                                                float* __restrict__ out)
{
    __shared__ bf16 As[64][72];
    __shared__ bf16 Bs[64][72];
    const int tid  = threadIdx.x;
    const int wid  = tid >> 6, lane = tid & 63;
    const int quad = lane >> 4, l15 = lane & 15;
    const int nbase = blockIdx.x * 64;
    const int mbase = blockIdx.y * 64;
    const int m0 = wid * 16;

    f32x4 acc[4];
#pragma unroll
    for (int i = 0; i < 4; ++i) acc[i] = (f32x4){0.f, 0.f, 0.f, 0.f};

    for (int kt = 0; kt < E / 64; ++kt) {
        const int kb = kt * 64;
        __syncthreads();
#pragma unroll
        for (int i = 0; i < 2; ++i) {
            int slot = tid + i * 256;
            int row = slot >> 3, kg = slot & 7;
            *(uint4*)&As[row][kg * 8] = *(const uint4*)&A[(size_t)(mbase + row) * E + kb + kg * 8];
            *(uint4*)&Bs[row][kg * 8] = *(const uint4*)&W[(size_t)(nbase + row) * E + kb + kg * 8];
        }
        __syncthreads();
        bf16x8 a0 = *(bf16x8*)&As[m0 + l15][quad * 8];
        bf16x8 a1 = *(bf16x8*)&As[m0 + l15][32 + quad * 8];
#pragma unroll
        for (int nt = 0; nt < 4; ++nt) {
            bf16x8 b0 = *(bf16x8*)&Bs[nt * 16 + l15][quad * 8];
            bf16x8 b1 = *(bf16x8*)&Bs[nt * 16 + l15][32 + quad * 8];
            acc[nt] = __builtin_amdgcn_mfma_f32_16x16x32_bf16(a0, b0, acc[nt], 0, 0, 0);
            acc[nt] = __builtin_amdgcn_mfma_f32_16x16x32_bf16(a1, b1, acc[nt], 0, 0, 0);
        }
    }
#pragma unroll
    for (int nt = 0; nt < 4; ++nt) {
        int col = nbase + nt * 16 + l15;
        float bv = (float)bias[col];
#pragma unroll
        for (int r = 0; r < 4; ++r) {
            int row = mbase + m0 + quad * 4 + r;
            out[(size_t)row * E + col] = acc[nt][r] + bv;
        }
    }
}

// ---------------------------------------------------------------------------
extern "C" void kernel_launch(void* const* d_in, const int* in_sizes, int n_in,
                              void* d_out, int out_size, void* d_ws, size_t ws_size,
                              hipStream_t stream)
{
    char* ws = (char*)d_ws;
    const size_t MB = (size_t)1 << 20;
    bf16* Qw   = (bf16*)(ws + 0 * MB);        // 12 MB: Q|K|V planar cat
    bf16* Kw   = (bf16*)(ws + 4 * MB);
    bf16* Vw   = (bf16*)(ws + 8 * MB);
    bf16* Ab   = (bf16*)(ws + 12 * MB);       // 4 MB combined attn out (bf16)
    unsigned long long* bitsT = (unsigned long long*)(ws + 16 * MB); // 2 MB
    bf16* xb   = (bf16*)(ws + 18 * MB);       // 4 MB
    bf16* Wcat = (bf16*)(ws + 22 * MB);       // 1.5 MB
    bf16* Wob  = (bf16*)(ws + 24 * MB);       // 0.5 MB
    bf16* bcat = (bf16*)(ws + 25 * MB);
    bf16* bob  = (bf16*)(ws + 25 * MB + 8192);
    float* Opart = (float*)(ws + 26 * MB);    // nsplit x 8 MB

    // 5-way K-split (1280 blocks = exactly 5 blocks/CU with 32 KiB LDS)
    // when the workspace allows; else 4; else 2.
    int nsplit = (ws_size >= 68 * MB) ? 5 : (ws_size >= 59 * MB) ? 4 : 2;
    int ktper  = (S / 64 + nsplit - 1) / nsplit;
    float* Lpart = (float*)(ws + 26 * MB + (size_t)nsplit * 8 * MB);

    hipLaunchKernelGGL(prep, dim3(2048), dim3(256), 0, stream,
                       d_in[9], bitsT,
                       (const float*)d_in[0], (const float*)d_in[1],
                       (const float*)d_in[3], (const float*)d_in[5],
                       (const float*)d_in[7], (const float*)d_in[2],
                       (const float*)d_in[4], (const float*)d_in[6],
                       (const float*)d_in[8],
                       xb, Wcat, Wob, bcat, bob);
    hipLaunchKernelGGL(gemm_qkv, dim3(24, 64), dim3(256), 0, stream,
                       xb, Wcat, bcat, Qw);
    hipLaunchKernelGGL(attn, dim3(S / 128, H, nsplit), dim3(256), 0, stream,
                       Qw, Kw, Vw, bitsT, Opart, Lpart, ktper);
    hipLaunchKernelGGL(combine, dim3(1024), dim3(256), 0, stream,
                       Opart, Lpart, Ab, nsplit);
    hipLaunchKernelGGL(gemm_out, dim3(8, 64), dim3(256), 0, stream,
                       Ab, Wob, bob, (float*)d_out);
}